// Round 11
// baseline (129.742 us; speedup 1.0000x reference)
//
#include <hip/hip_runtime.h>
#include <cstdint>
#include <cstddef>
#include <cfloat>
#include <cmath>

#define NB    32
#define NIN   512
#define NMEM  32768
#define NCELL 64
#define NVIS  17
#define NK    16
#define NBLK  64               // stage-1 blocks per batch
#define RPB   (NMEM / NBLK)    // 512 rows per block
#define NCAND (NBLK * NK)      // 1024 candidates per batch

// output flat layout (f32 elements)
#define OFF_RV  0
#define OFF_RW  2048
#define OFF_VIS 1050624
#define OFF_WV  1085440
#define OFF_IG  1087488
#define OFF_WG  1088032

// scratch layout (f32-element offsets from scr_base + b*scr_stride)
#define SCR_RQ  0        // 64 f32
#define SCR_CV  64       // 1024 f32
#define SCR_CI  1088     // 1024 i32 (ends 2112)
#define SCR_STRIDE_WS 2112

// ---------------- A: interface GEMVs, grid (NB, 5 row-groups) ---------------
__global__ __launch_bounds__(256) void kA(
    const float* __restrict__ xi,
    const float* __restrict__ Wrq, const float* __restrict__ brq,
    const float* __restrict__ Wwv, const float* __restrict__ bwv,
    const float* __restrict__ Wig, const float* __restrict__ big,
    const float* __restrict__ Wwg, const float* __restrict__ bwg,
    float* __restrict__ scr_base, int scr_stride,
    float* __restrict__ out)
{
    int b = blockIdx.x;
    int tid = threadIdx.x;
    float* rq_scr = scr_base + (size_t)b * scr_stride + SCR_RQ;
    __shared__ float sxi[NIN];
    for (int i = tid; i < NIN; i += 256)
        sxi[i] = xi[(size_t)b * NIN + i];
    __syncthreads();
    int g = tid >> 3, sub = tid & 7;          // 8 lanes per row, 32 rows/block
    int row = blockIdx.y * 32 + g;
    if (row < 146) {
        const float* W; float bias; int kind, r;
        if (row < 64)       { r = row;       W = Wrq + (size_t)r * NIN; bias = brq[r]; kind = 0; }
        else if (row < 128) { r = row - 64;  W = Wwv + (size_t)r * NIN; bias = bwv[r]; kind = 1; }
        else if (row < 145) { r = row - 128; W = Wig + (size_t)r * NIN; bias = big[r]; kind = 2; }
        else                { r = 0;         W = Wwg;                   bias = bwg[0]; kind = 3; }
        float acc = 0.f;
        const float* wp = W   + sub * 64;
        const float* xp = sxi + sub * 64;
        for (int j = 0; j < 64; ++j)
            acc = fmaf(wp[j], xp[j], acc);
        acc += __shfl_xor(acc, 1);
        acc += __shfl_xor(acc, 2);
        acc += __shfl_xor(acc, 4);
        if (sub == 0) {
            float x = acc + bias;
            if (kind == 0)      rq_scr[r] = tanhf(x);
            else if (kind == 1) out[OFF_WV + b * NCELL + r] = tanhf(x);
            else if (kind == 2) out[OFF_IG + b * NVIS + r]  = 1.f / (1.f + expf(-x));
            else                out[OFF_WG + b]             = 1.f / (1.f + expf(-x));
        }
    }
}

// ---------------- B: fused sims + hierarchical per-block top-16 -------------
// grid (NBLK, NB). 16 lanes per row -> every load instruction is a fully
// contiguous 1 KB wave access. In ws mode each block zeroes its RW slice.
__global__ __launch_bounds__(256) void kB(
    const float* __restrict__ mem,
    float* __restrict__ scr_base, int scr_stride, int kb_zero,
    float* __restrict__ out)
{
    int b   = blockIdx.y;
    int blk = blockIdx.x;
    int tid = threadIdx.x;
    int w = tid >> 6, lane = tid & 63;
    int sub16 = lane & 15, grp4 = lane >> 4;
    float* scr = scr_base + (size_t)b * scr_stride;
    __shared__ float ssim[4][128];
    __shared__ float wcv[64];
    __shared__ int   wci[64];

    if (kb_zero) {
        // zero own 512-float slice of batch b's read_weights row
        float2 z; z.x = z.y = 0.f;
        ((float2*)(out + OFF_RW + (size_t)b * NMEM + blk * RPB))[tid] = z;
    }

    float rq4[4];
    for (int e = 0; e < 4; ++e) rq4[e] = scr[SCR_RQ + sub16 * 4 + e];

    const float* mb = mem + (size_t)b * NMEM * NCELL + (size_t)(blk * RPB + w * 128) * NCELL;

    // 128 rows per wave; 16 rows per iter (4 slots x 4 rows), 4 loads in flight
    for (int it = 0; it < 8; ++it) {
        int rbase = it * 16;
        const float* p0 = mb + (size_t)(rbase +  0 + grp4) * NCELL + sub16 * 4;
        const float* p1 = mb + (size_t)(rbase +  4 + grp4) * NCELL + sub16 * 4;
        const float* p2 = mb + (size_t)(rbase +  8 + grp4) * NCELL + sub16 * 4;
        const float* p3 = mb + (size_t)(rbase + 12 + grp4) * NCELL + sub16 * 4;
        float4 x0 = *(const float4*)p0;
        float4 x1 = *(const float4*)p1;
        float4 x2 = *(const float4*)p2;
        float4 x3 = *(const float4*)p3;

        float s0 = 0.f, s1 = 0.f, s2 = 0.f, s3 = 0.f;
        s0 = fmaf(x0.x, rq4[0], s0); s0 = fmaf(x0.y, rq4[1], s0);
        s0 = fmaf(x0.z, rq4[2], s0); s0 = fmaf(x0.w, rq4[3], s0);
        s1 = fmaf(x1.x, rq4[0], s1); s1 = fmaf(x1.y, rq4[1], s1);
        s1 = fmaf(x1.z, rq4[2], s1); s1 = fmaf(x1.w, rq4[3], s1);
        s2 = fmaf(x2.x, rq4[0], s2); s2 = fmaf(x2.y, rq4[1], s2);
        s2 = fmaf(x2.z, rq4[2], s2); s2 = fmaf(x2.w, rq4[3], s2);
        s3 = fmaf(x3.x, rq4[0], s3); s3 = fmaf(x3.y, rq4[1], s3);
        s3 = fmaf(x3.z, rq4[2], s3); s3 = fmaf(x3.w, rq4[3], s3);

        s0 += __shfl_xor(s0, 1); s0 += __shfl_xor(s0, 2);
        s0 += __shfl_xor(s0, 4); s0 += __shfl_xor(s0, 8);
        s1 += __shfl_xor(s1, 1); s1 += __shfl_xor(s1, 2);
        s1 += __shfl_xor(s1, 4); s1 += __shfl_xor(s1, 8);
        s2 += __shfl_xor(s2, 1); s2 += __shfl_xor(s2, 2);
        s2 += __shfl_xor(s2, 4); s2 += __shfl_xor(s2, 8);
        s3 += __shfl_xor(s3, 1); s3 += __shfl_xor(s3, 2);
        s3 += __shfl_xor(s3, 4); s3 += __shfl_xor(s3, 8);

        if (sub16 == 0) {
            ssim[w][rbase +  0 + grp4] = s0;
            ssim[w][rbase +  4 + grp4] = s1;
            ssim[w][rbase +  8 + grp4] = s2;
            ssim[w][rbase + 12 + grp4] = s3;
        }
    }
    __syncthreads();

    // per-wave top-16 over 128 values (each lane owns 2)
    int gbase = blk * RPB + w * 128;
    float v[2]; int gi[2];
    for (int j = 0; j < 2; ++j) {
        v[j]  = ssim[w][lane * 2 + j];
        gi[j] = gbase + lane * 2 + j;
    }
    for (int r = 0; r < NK; ++r) {
        float bv = v[0]; int bi = gi[0];
        if (v[1] > bv || (v[1] == bv && gi[1] < bi)) { bv = v[1]; bi = gi[1]; }
        for (int off = 32; off >= 1; off >>= 1) {
            float ov = __shfl_xor(bv, off); int oi = __shfl_xor(bi, off);
            if (ov > bv || (ov == bv && oi < bi)) { bv = ov; bi = oi; }
        }
        for (int j = 0; j < 2; ++j)
            if (gi[j] == bi) { v[j] = -FLT_MAX; gi[j] = 0x7fffffff; }
        if (lane == 0) { wcv[w * 16 + r] = bv; wci[w * 16 + r] = bi; }
    }
    __syncthreads();

    // wave 0 merges 4x16 wave candidates -> block top-16 into scratch
    if (w == 0) {
        float mv2 = wcv[lane]; int mi2 = wci[lane];
        float* ovp = scr + SCR_CV + blk * NK;
        int*   oip = (int*)(scr + SCR_CI) + blk * NK;
        for (int r = 0; r < NK; ++r) {
            float bv = mv2; int bi = mi2;
            for (int off = 32; off >= 1; off >>= 1) {
                float ov = __shfl_xor(bv, off); int oi = __shfl_xor(bi, off);
                if (ov > bv || (ov == bv && oi < bi)) { bv = ov; bi = oi; }
            }
            if (mi2 == bi) { mv2 = -FLT_MAX; mi2 = 0x7fffffff; }
            if (lane == 0) { ovp[r] = bv; oip[r] = bi; }
        }
    }
}

// ------- C: final top-16, lum score, softmax, (zero+)scatter, RV/VIS --------
__global__ __launch_bounds__(256) void kC(
    const float* __restrict__ mem, const int* __restrict__ lum,
    const float* __restrict__ scr_base, int scr_stride, int kc_zero,
    float* __restrict__ out)
{
    int b = blockIdx.x;
    int tid = threadIdx.x;
    int w = tid >> 6, lane = tid & 63;
    float* rwrow = out + OFF_RW + (size_t)b * NMEM;
    const float* scr = scr_base + (size_t)b * scr_stride;
    __shared__ float lv[NCAND];
    __shared__ int   li[NCAND];
    __shared__ int   pos_s[NVIS];
    __shared__ float sc_s[NVIS];
    __shared__ float rw_s[NVIS];
    __shared__ float pacc[4][NCELL];

    for (int j = 0; j < 4; ++j) {
        int e = tid * 4 + j;
        lv[e] = scr[SCR_CV + e];
        li[e] = ((const int*)(scr + SCR_CI))[e];
    }
    __syncthreads();

    if (w == 0) {
        // final top-16 over 1024 candidates (each lane owns 16)
        float v[16]; int gi[16];
        for (int j = 0; j < 16; ++j) { v[j] = lv[lane * 16 + j]; gi[j] = li[lane * 16 + j]; }
        for (int r = 0; r < NK; ++r) {
            float bv = v[0]; int bi = gi[0];
            for (int j = 1; j < 16; ++j)
                if (v[j] > bv || (v[j] == bv && gi[j] < bi)) { bv = v[j]; bi = gi[j]; }
            for (int off = 32; off >= 1; off >>= 1) {
                float ov = __shfl_xor(bv, off); int oi = __shfl_xor(bi, off);
                if (ov > bv || (ov == bv && oi < bi)) { bv = ov; bi = oi; }
            }
            for (int j = 0; j < 16; ++j)
                if (gi[j] == bi) { v[j] = -FLT_MAX; gi[j] = 0x7fffffff; }
            if (lane == 0) { pos_s[r] = bi & (NMEM - 1); sc_s[r] = bv; }
        }
        // least-used position score: dot(rq, mem[lum]) across 64 lanes
        int p16 = lum[b] & (NMEM - 1);
        float x = mem[((size_t)b * NMEM + p16) * NCELL + lane] * scr[SCR_RQ + lane];
        for (int off = 32; off >= 1; off >>= 1) x += __shfl_xor(x, off);
        if (lane == 0) { pos_s[NK] = p16; sc_s[NK] = x; }
    }
    __syncthreads();

    if (w == 0) {
        // softmax over 17 scores
        float sc = (lane < NVIS) ? sc_s[lane] : -FLT_MAX;
        float mx = sc;
        for (int off = 32; off >= 1; off >>= 1) mx = fmaxf(mx, __shfl_xor(mx, off));
        float e = (lane < NVIS) ? expf(sc - mx) : 0.f;
        float sum = e;
        for (int off = 32; off >= 1; off >>= 1) sum += __shfl_xor(sum, off);
        if (lane < NVIS) rw_s[lane] = e / sum;
    }
    __syncthreads();

    if (kc_zero) {
        // fallback: zero own RW row here (scratch lived in it; now staged)
        for (int it = 0; it < 128; ++it)
            rwrow[it * 256 + tid] = 0.f;
    }

    // visible copy + read_vectors partials (wave w takes rows w, w+4, ...)
    float acc = 0.f;
    for (int vv = w; vv < NVIS; vv += 4) {
        int p = pos_s[vv] & (NMEM - 1);
        float hv = mem[((size_t)b * NMEM + p) * NCELL + lane];
        out[OFF_VIS + ((size_t)b * NVIS + vv) * NCELL + lane] = hv;  // exact passthrough
        acc = fmaf(rw_s[vv], hv, acc);
    }
    pacc[w][lane] = acc;
    __syncthreads();

    if (tid < NCELL) {
        float s = pacc[0][tid] + pacc[1][tid] + pacc[2][tid] + pacc[3][tid];
        out[OFF_RV + b * NCELL + tid] = s;
    }
    // scatter read weights (lum = last position wins duplicates, np semantics)
    if (tid < NVIS) {
        int p = pos_s[tid] & (NMEM - 1);
        bool dup = (tid < NK) && (p == pos_s[NK]);
        if (!dup) rwrow[p] = rw_s[tid];
    }
}

extern "C" void kernel_launch(void* const* d_in, const int* in_sizes, int n_in,
                              void* d_out, int out_size, void* d_ws, size_t ws_size,
                              hipStream_t stream)
{
    const float* xi  = (const float*)d_in[0];
    const float* mem = (const float*)d_in[1];
    const int*   lum = (const int*)d_in[2];
    const float* Wrq = (const float*)d_in[3];
    const float* brq = (const float*)d_in[4];
    const float* Wwv = (const float*)d_in[5];
    const float* bwv = (const float*)d_in[6];
    const float* Wig = (const float*)d_in[7];
    const float* big = (const float*)d_in[8];
    const float* Wwg = (const float*)d_in[9];
    const float* bwg = (const float*)d_in[10];
    float* out = (float*)d_out;

    // Scratch: d_ws if big enough, else inside the RW output region (round-8
    // validated fallback).
    bool use_ws = (d_ws != nullptr) && (ws_size >= (size_t)NB * SCR_STRIDE_WS * 4);
    float* scrb = use_ws ? (float*)d_ws : out + OFF_RW;
    int    scrs = use_ws ? SCR_STRIDE_WS : NMEM;
    int    kb_zero = use_ws ? 1 : 0;   // ws mode: kB zeroes RW slices in parallel
    int    kc_zero = use_ws ? 0 : 1;   // fallback: kC zeroes (round-8 behavior)

    kA<<<dim3(NB, 5), dim3(256), 0, stream>>>(xi, Wrq, brq, Wwv, bwv, Wig, big,
                                              Wwg, bwg, scrb, scrs, out);
    kB<<<dim3(NBLK, NB), dim3(256), 0, stream>>>(mem, scrb, scrs, kb_zero, out);
    kC<<<dim3(NB), dim3(256), 0, stream>>>(mem, lum, scrb, scrs, kc_zero, out);
}

// Round 12
// 126.301 us; speedup vs baseline: 1.0272x; 1.0272x over previous
//
#include <hip/hip_runtime.h>
#include <cstdint>
#include <cstddef>
#include <cfloat>
#include <cmath>

#define NB    32
#define NIN   512
#define NMEM  32768
#define NCELL 64
#define NVIS  17
#define NK    16
#define NBLK  32               // stage-1 blocks per batch
#define RPB   (NMEM / NBLK)    // 1024 rows per block
#define NCAND (NBLK * NK)      // 512 candidates per batch

// output flat layout (f32 elements)
#define OFF_RV  0
#define OFF_RW  2048
#define OFF_VIS 1050624
#define OFF_WV  1085440
#define OFF_IG  1087488
#define OFF_WG  1088032

// scratch layout (f32-element offsets from scr_base + b*scr_stride)
#define SCR_RQ  0       // 64 f32
#define SCR_CV  64      // 512 f32
#define SCR_CI  576     // 512 i32  (ends 1088)
#define SCR_STRIDE_WS 1088

// ---------------- A: interface GEMVs, grid (NB, 5 row-groups) ---------------
__global__ __launch_bounds__(256) void kA(
    const float* __restrict__ xi,
    const float* __restrict__ Wrq, const float* __restrict__ brq,
    const float* __restrict__ Wwv, const float* __restrict__ bwv,
    const float* __restrict__ Wig, const float* __restrict__ big,
    const float* __restrict__ Wwg, const float* __restrict__ bwg,
    float* __restrict__ scr_base, int scr_stride,
    float* __restrict__ out)
{
    int b = blockIdx.x;
    int tid = threadIdx.x;
    float* rq_scr = scr_base + (size_t)b * scr_stride + SCR_RQ;
    __shared__ float sxi[NIN];
    for (int i = tid; i < NIN; i += 256)
        sxi[i] = xi[(size_t)b * NIN + i];
    __syncthreads();
    int g = tid >> 3, sub = tid & 7;          // 8 lanes per row, 32 rows/block
    int row = blockIdx.y * 32 + g;
    if (row < 146) {
        const float* W; float bias; int kind, r;
        if (row < 64)       { r = row;       W = Wrq + (size_t)r * NIN; bias = brq[r]; kind = 0; }
        else if (row < 128) { r = row - 64;  W = Wwv + (size_t)r * NIN; bias = bwv[r]; kind = 1; }
        else if (row < 145) { r = row - 128; W = Wig + (size_t)r * NIN; bias = big[r]; kind = 2; }
        else                { r = 0;         W = Wwg;                   bias = bwg[0]; kind = 3; }
        float acc = 0.f;
        const float* wp = W   + sub * 64;
        const float* xp = sxi + sub * 64;
        for (int j = 0; j < 64; ++j)
            acc = fmaf(wp[j], xp[j], acc);
        acc += __shfl_xor(acc, 1);
        acc += __shfl_xor(acc, 2);
        acc += __shfl_xor(acc, 4);
        if (sub == 0) {
            float x = acc + bias;
            if (kind == 0)      rq_scr[r] = tanhf(x);
            else if (kind == 1) out[OFF_WV + b * NCELL + r] = tanhf(x);
            else if (kind == 2) out[OFF_IG + b * NVIS + r]  = 1.f / (1.f + expf(-x));
            else                out[OFF_WG + b]             = 1.f / (1.f + expf(-x));
        }
    }
}

// ---------------- B: fused sims + hierarchical per-block top-16 -------------
// grid (NBLK, NB). ONE THREAD = ONE ROW (4 rows/thread): the streaming loop
// has zero DS ops, zero exec masks -- pure global loads + FMA. Per-wave
// top-16 butterfly runs once, on register-resident sims.
__global__ __launch_bounds__(256) void kB(
    const float* __restrict__ mem,
    float* __restrict__ scr_base, int scr_stride, int kb_zero,
    float* __restrict__ out)
{
    int b   = blockIdx.y;
    int blk = blockIdx.x;
    int tid = threadIdx.x;
    int w = tid >> 6, lane = tid & 63;
    float* scr = scr_base + (size_t)b * scr_stride;
    __shared__ float srq[NCELL];
    __shared__ float wcv[64];
    __shared__ int   wci[64];

    if (kb_zero) {
        // zero own 1024-float slice of batch b's read_weights row
        float4 z; z.x = z.y = z.z = z.w = 0.f;
        ((float4*)(out + OFF_RW + (size_t)b * NMEM + blk * RPB))[tid] = z;
    }

    if (tid < NCELL) srq[tid] = scr[SCR_RQ + tid];
    __syncthreads();

    // 4 consecutive rows per thread; row dot fully in-register
    int row0 = blk * RPB + w * 256 + lane * 4;
    const float* rp0 = mem + ((size_t)b * NMEM + row0) * NCELL;
    float v[4]; int gi[4];
    for (int j = 0; j < 4; ++j) {
        const float* r = rp0 + (size_t)j * NCELL;
        float acc = 0.f;
        #pragma unroll
        for (int k = 0; k < 16; ++k) {
            float4 x = *(const float4*)(r + k * 4);
            float4 q = *(const float4*)(srq + k * 4);   // LDS broadcast read
            acc = fmaf(x.x, q.x, acc);
            acc = fmaf(x.y, q.y, acc);
            acc = fmaf(x.z, q.z, acc);
            acc = fmaf(x.w, q.w, acc);
        }
        v[j]  = acc;
        gi[j] = row0 + j;
    }

    // per-wave top-16 over 256 values (each lane owns 4, register-resident)
    for (int r = 0; r < NK; ++r) {
        float bv = v[0]; int bi = gi[0];
        for (int j = 1; j < 4; ++j)
            if (v[j] > bv || (v[j] == bv && gi[j] < bi)) { bv = v[j]; bi = gi[j]; }
        for (int off = 32; off >= 1; off >>= 1) {
            float ov = __shfl_xor(bv, off); int oi = __shfl_xor(bi, off);
            if (ov > bv || (ov == bv && oi < bi)) { bv = ov; bi = oi; }
        }
        for (int j = 0; j < 4; ++j)
            if (gi[j] == bi) { v[j] = -FLT_MAX; gi[j] = 0x7fffffff; }
        if (lane == 0) { wcv[w * 16 + r] = bv; wci[w * 16 + r] = bi; }
    }
    __syncthreads();

    // wave 0 merges 4x16 wave candidates -> block top-16 into scratch
    if (w == 0) {
        float mv2 = wcv[lane]; int mi2 = wci[lane];
        float* ovp = scr + SCR_CV + blk * NK;
        int*   oip = (int*)(scr + SCR_CI) + blk * NK;
        for (int r = 0; r < NK; ++r) {
            float bv = mv2; int bi = mi2;
            for (int off = 32; off >= 1; off >>= 1) {
                float ov = __shfl_xor(bv, off); int oi = __shfl_xor(bi, off);
                if (ov > bv || (ov == bv && oi < bi)) { bv = ov; bi = oi; }
            }
            if (mi2 == bi) { mv2 = -FLT_MAX; mi2 = 0x7fffffff; }
            if (lane == 0) { ovp[r] = bv; oip[r] = bi; }
        }
    }
}

// ------- C: final top-16, lum score, softmax, (zero+)scatter, RV/VIS --------
__global__ __launch_bounds__(256) void kC(
    const float* __restrict__ mem, const int* __restrict__ lum,
    const float* __restrict__ scr_base, int scr_stride, int kc_zero,
    float* __restrict__ out)
{
    int b = blockIdx.x;
    int tid = threadIdx.x;
    int w = tid >> 6, lane = tid & 63;
    float* rwrow = out + OFF_RW + (size_t)b * NMEM;
    const float* scr = scr_base + (size_t)b * scr_stride;
    __shared__ float lv[NCAND];
    __shared__ int   li[NCAND];
    __shared__ int   pos_s[NVIS];
    __shared__ float sc_s[NVIS];
    __shared__ float rw_s[NVIS];
    __shared__ float pacc[4][NCELL];

    for (int j = 0; j < 2; ++j) {
        int e = tid * 2 + j;
        lv[e] = scr[SCR_CV + e];
        li[e] = ((const int*)(scr + SCR_CI))[e];
    }
    __syncthreads();

    if (w == 0) {
        // final top-16 over 512 candidates (each lane owns 8)
        float v[8]; int gi[8];
        for (int j = 0; j < 8; ++j) { v[j] = lv[lane * 8 + j]; gi[j] = li[lane * 8 + j]; }
        for (int r = 0; r < NK; ++r) {
            float bv = v[0]; int bi = gi[0];
            for (int j = 1; j < 8; ++j)
                if (v[j] > bv || (v[j] == bv && gi[j] < bi)) { bv = v[j]; bi = gi[j]; }
            for (int off = 32; off >= 1; off >>= 1) {
                float ov = __shfl_xor(bv, off); int oi = __shfl_xor(bi, off);
                if (ov > bv || (ov == bv && oi < bi)) { bv = ov; bi = oi; }
            }
            for (int j = 0; j < 8; ++j)
                if (gi[j] == bi) { v[j] = -FLT_MAX; gi[j] = 0x7fffffff; }
            if (lane == 0) { pos_s[r] = bi & (NMEM - 1); sc_s[r] = bv; }
        }
        // least-used position score: dot(rq, mem[lum]) across 64 lanes
        int p16 = lum[b] & (NMEM - 1);
        float x = mem[((size_t)b * NMEM + p16) * NCELL + lane] * scr[SCR_RQ + lane];
        for (int off = 32; off >= 1; off >>= 1) x += __shfl_xor(x, off);
        if (lane == 0) { pos_s[NK] = p16; sc_s[NK] = x; }
    }
    __syncthreads();

    if (w == 0) {
        // softmax over 17 scores
        float sc = (lane < NVIS) ? sc_s[lane] : -FLT_MAX;
        float mx = sc;
        for (int off = 32; off >= 1; off >>= 1) mx = fmaxf(mx, __shfl_xor(mx, off));
        float e = (lane < NVIS) ? expf(sc - mx) : 0.f;
        float sum = e;
        for (int off = 32; off >= 1; off >>= 1) sum += __shfl_xor(sum, off);
        if (lane < NVIS) rw_s[lane] = e / sum;
    }
    __syncthreads();

    if (kc_zero) {
        // fallback: zero own RW row here (scratch lived in it; now staged)
        for (int it = 0; it < 128; ++it)
            rwrow[it * 256 + tid] = 0.f;
    }

    // visible copy + read_vectors partials (wave w takes rows w, w+4, ...)
    float acc = 0.f;
    for (int vv = w; vv < NVIS; vv += 4) {
        int p = pos_s[vv] & (NMEM - 1);
        float hv = mem[((size_t)b * NMEM + p) * NCELL + lane];
        out[OFF_VIS + ((size_t)b * NVIS + vv) * NCELL + lane] = hv;  // exact passthrough
        acc = fmaf(rw_s[vv], hv, acc);
    }
    pacc[w][lane] = acc;
    __syncthreads();

    if (tid < NCELL) {
        float s = pacc[0][tid] + pacc[1][tid] + pacc[2][tid] + pacc[3][tid];
        out[OFF_RV + b * NCELL + tid] = s;
    }
    // scatter read weights (lum = last position wins duplicates, np semantics)
    if (tid < NVIS) {
        int p = pos_s[tid] & (NMEM - 1);
        bool dup = (tid < NK) && (p == pos_s[NK]);
        if (!dup) rwrow[p] = rw_s[tid];
    }
}

extern "C" void kernel_launch(void* const* d_in, const int* in_sizes, int n_in,
                              void* d_out, int out_size, void* d_ws, size_t ws_size,
                              hipStream_t stream)
{
    const float* xi  = (const float*)d_in[0];
    const float* mem = (const float*)d_in[1];
    const int*   lum = (const int*)d_in[2];
    const float* Wrq = (const float*)d_in[3];
    const float* brq = (const float*)d_in[4];
    const float* Wwv = (const float*)d_in[5];
    const float* bwv = (const float*)d_in[6];
    const float* Wig = (const float*)d_in[7];
    const float* big = (const float*)d_in[8];
    const float* Wwg = (const float*)d_in[9];
    const float* bwg = (const float*)d_in[10];
    float* out = (float*)d_out;

    // Scratch: d_ws if big enough, else inside the RW output region (round-8
    // validated fallback).
    bool use_ws = (d_ws != nullptr) && (ws_size >= (size_t)NB * SCR_STRIDE_WS * 4);
    float* scrb = use_ws ? (float*)d_ws : out + OFF_RW;
    int    scrs = use_ws ? SCR_STRIDE_WS : NMEM;
    int    kb_zero = use_ws ? 1 : 0;   // ws mode: kB zeroes RW slices in parallel
    int    kc_zero = use_ws ? 0 : 1;   // fallback: kC zeroes (round-8 behavior)

    kA<<<dim3(NB, 5), dim3(256), 0, stream>>>(xi, Wrq, brq, Wwv, bwv, Wig, big,
                                              Wwg, bwg, scrb, scrs, out);
    kB<<<dim3(NBLK, NB), dim3(256), 0, stream>>>(mem, scrb, scrs, kb_zero, out);
    kC<<<dim3(NB), dim3(256), 0, stream>>>(mem, lum, scrb, scrs, kc_zero, out);
}

// Round 13
// 94.742 us; speedup vs baseline: 1.3694x; 1.3331x over previous
//
#include <hip/hip_runtime.h>
#include <cstdint>
#include <cstddef>
#include <cfloat>
#include <cmath>

#define NB    32
#define NIN   512
#define NMEM  32768
#define NCELL 64
#define NVIS  17
#define NK    16
#define NBLK  32               // stage-1 blocks per batch
#define RPB   (NMEM / NBLK)    // 1024 rows per block
#define NCAND (NBLK * NK)      // 512 candidates per batch

// output flat layout (f32 elements)
#define OFF_RV  0
#define OFF_RW  2048
#define OFF_VIS 1050624
#define OFF_WV  1085440
#define OFF_IG  1087488
#define OFF_WG  1088032

// scratch layout (f32-element offsets from scr_base + b*scr_stride)
#define SCR_RQ  0       // 64 f32
#define SCR_CV  64      // 512 f32
#define SCR_CI  576     // 512 i32  (ends 1088)
#define SCR_STRIDE_WS 1088

// ---------------- A: interface GEMVs, grid (NB, 5 row-groups) ---------------
__global__ __launch_bounds__(256) void kA(
    const float* __restrict__ xi,
    const float* __restrict__ Wrq, const float* __restrict__ brq,
    const float* __restrict__ Wwv, const float* __restrict__ bwv,
    const float* __restrict__ Wig, const float* __restrict__ big,
    const float* __restrict__ Wwg, const float* __restrict__ bwg,
    float* __restrict__ scr_base, int scr_stride,
    float* __restrict__ out)
{
    int b = blockIdx.x;
    int tid = threadIdx.x;
    float* rq_scr = scr_base + (size_t)b * scr_stride + SCR_RQ;
    __shared__ float sxi[NIN];
    for (int i = tid; i < NIN; i += 256)
        sxi[i] = xi[(size_t)b * NIN + i];
    __syncthreads();
    int g = tid >> 3, sub = tid & 7;          // 8 lanes per row, 32 rows/block
    int row = blockIdx.y * 32 + g;
    if (row < 146) {
        const float* W; float bias; int kind, r;
        if (row < 64)       { r = row;       W = Wrq + (size_t)r * NIN; bias = brq[r]; kind = 0; }
        else if (row < 128) { r = row - 64;  W = Wwv + (size_t)r * NIN; bias = bwv[r]; kind = 1; }
        else if (row < 145) { r = row - 128; W = Wig + (size_t)r * NIN; bias = big[r]; kind = 2; }
        else                { r = 0;         W = Wwg;                   bias = bwg[0]; kind = 3; }
        float acc = 0.f;
        const float* wp = W   + sub * 64;
        const float* xp = sxi + sub * 64;
        for (int j = 0; j < 64; ++j)
            acc = fmaf(wp[j], xp[j], acc);
        acc += __shfl_xor(acc, 1);
        acc += __shfl_xor(acc, 2);
        acc += __shfl_xor(acc, 4);
        if (sub == 0) {
            float x = acc + bias;
            if (kind == 0)      rq_scr[r] = tanhf(x);
            else if (kind == 1) out[OFF_WV + b * NCELL + r] = tanhf(x);
            else if (kind == 2) out[OFF_IG + b * NVIS + r]  = 1.f / (1.f + expf(-x));
            else                out[OFF_WG + b]             = 1.f / (1.f + expf(-x));
        }
    }
}

// ---------------- B: fused sims + hierarchical per-block top-16 -------------
// grid (NBLK, NB). DENSE loads: 16 lanes per row, every dwordx4 covers 4
// whole rows = 1 KB contiguous. Butterfly reduce within 16-lane groups.
__global__ __launch_bounds__(256) void kB(
    const float* __restrict__ mem,
    float* __restrict__ scr_base, int scr_stride, int kb_zero,
    float* __restrict__ out)
{
    int b   = blockIdx.y;
    int blk = blockIdx.x;
    int tid = threadIdx.x;
    int w = tid >> 6, lane = tid & 63;
    int sub16 = lane & 15, grp4 = lane >> 4;
    float* scr = scr_base + (size_t)b * scr_stride;
    __shared__ float ssim[4][256];
    __shared__ float wcv[64];
    __shared__ int   wci[64];

    if (kb_zero) {
        // zero own 1024-float slice of batch b's read_weights row
        float4 z; z.x = z.y = z.z = z.w = 0.f;
        ((float4*)(out + OFF_RW + (size_t)b * NMEM + blk * RPB))[tid] = z;
    }

    float rq4[4];
    for (int e = 0; e < 4; ++e) rq4[e] = scr[SCR_RQ + sub16 * 4 + e];

    const float* mb = mem + (size_t)b * NMEM * NCELL + (size_t)(blk * RPB + w * 256) * NCELL;

    // 256 rows per wave; 16 rows per iter via 4 dense 1KB load instructions
    for (int it = 0; it < 16; ++it) {
        int rbase = it * 16;
        const float* p0 = mb + (size_t)(rbase +  0 + grp4) * NCELL + sub16 * 4;
        const float* p1 = mb + (size_t)(rbase +  4 + grp4) * NCELL + sub16 * 4;
        const float* p2 = mb + (size_t)(rbase +  8 + grp4) * NCELL + sub16 * 4;
        const float* p3 = mb + (size_t)(rbase + 12 + grp4) * NCELL + sub16 * 4;
        float4 x0 = *(const float4*)p0;
        float4 x1 = *(const float4*)p1;
        float4 x2 = *(const float4*)p2;
        float4 x3 = *(const float4*)p3;

        float s0 = 0.f, s1 = 0.f, s2 = 0.f, s3 = 0.f;
        s0 = fmaf(x0.x, rq4[0], s0); s0 = fmaf(x0.y, rq4[1], s0);
        s0 = fmaf(x0.z, rq4[2], s0); s0 = fmaf(x0.w, rq4[3], s0);
        s1 = fmaf(x1.x, rq4[0], s1); s1 = fmaf(x1.y, rq4[1], s1);
        s1 = fmaf(x1.z, rq4[2], s1); s1 = fmaf(x1.w, rq4[3], s1);
        s2 = fmaf(x2.x, rq4[0], s2); s2 = fmaf(x2.y, rq4[1], s2);
        s2 = fmaf(x2.z, rq4[2], s2); s2 = fmaf(x2.w, rq4[3], s2);
        s3 = fmaf(x3.x, rq4[0], s3); s3 = fmaf(x3.y, rq4[1], s3);
        s3 = fmaf(x3.z, rq4[2], s3); s3 = fmaf(x3.w, rq4[3], s3);

        s0 += __shfl_xor(s0, 1); s0 += __shfl_xor(s0, 2);
        s0 += __shfl_xor(s0, 4); s0 += __shfl_xor(s0, 8);
        s1 += __shfl_xor(s1, 1); s1 += __shfl_xor(s1, 2);
        s1 += __shfl_xor(s1, 4); s1 += __shfl_xor(s1, 8);
        s2 += __shfl_xor(s2, 1); s2 += __shfl_xor(s2, 2);
        s2 += __shfl_xor(s2, 4); s2 += __shfl_xor(s2, 8);
        s3 += __shfl_xor(s3, 1); s3 += __shfl_xor(s3, 2);
        s3 += __shfl_xor(s3, 4); s3 += __shfl_xor(s3, 8);

        if (sub16 == 0) {
            ssim[w][rbase +  0 + grp4] = s0;
            ssim[w][rbase +  4 + grp4] = s1;
            ssim[w][rbase +  8 + grp4] = s2;
            ssim[w][rbase + 12 + grp4] = s3;
        }
    }
    __syncthreads();

    // per-wave top-16 over 256 values (each lane owns 4)
    int gbase = blk * RPB + w * 256;
    float v[4]; int gi[4];
    for (int j = 0; j < 4; ++j) {
        v[j]  = ssim[w][lane * 4 + j];
        gi[j] = gbase + lane * 4 + j;
    }
    for (int r = 0; r < NK; ++r) {
        float bv = v[0]; int bi = gi[0];
        for (int j = 1; j < 4; ++j)
            if (v[j] > bv || (v[j] == bv && gi[j] < bi)) { bv = v[j]; bi = gi[j]; }
        for (int off = 32; off >= 1; off >>= 1) {
            float ov = __shfl_xor(bv, off); int oi = __shfl_xor(bi, off);
            if (ov > bv || (ov == bv && oi < bi)) { bv = ov; bi = oi; }
        }
        for (int j = 0; j < 4; ++j)
            if (gi[j] == bi) { v[j] = -FLT_MAX; gi[j] = 0x7fffffff; }
        if (lane == 0) { wcv[w * 16 + r] = bv; wci[w * 16 + r] = bi; }
    }
    __syncthreads();

    // wave 0 merges 4x16 wave candidates -> block top-16 into scratch
    if (w == 0) {
        float mv2 = wcv[lane]; int mi2 = wci[lane];
        float* ovp = scr + SCR_CV + blk * NK;
        int*   oip = (int*)(scr + SCR_CI) + blk * NK;
        for (int r = 0; r < NK; ++r) {
            float bv = mv2; int bi = mi2;
            for (int off = 32; off >= 1; off >>= 1) {
                float ov = __shfl_xor(bv, off); int oi = __shfl_xor(bi, off);
                if (ov > bv || (ov == bv && oi < bi)) { bv = ov; bi = oi; }
            }
            if (mi2 == bi) { mv2 = -FLT_MAX; mi2 = 0x7fffffff; }
            if (lane == 0) { ovp[r] = bv; oip[r] = bi; }
        }
    }
}

// ------- C: final top-16, lum score, softmax, (zero+)scatter, RV/VIS --------
__global__ __launch_bounds__(256) void kC(
    const float* __restrict__ mem, const int* __restrict__ lum,
    const float* __restrict__ scr_base, int scr_stride, int kc_zero,
    float* __restrict__ out)
{
    int b = blockIdx.x;
    int tid = threadIdx.x;
    int w = tid >> 6, lane = tid & 63;
    float* rwrow = out + OFF_RW + (size_t)b * NMEM;
    const float* scr = scr_base + (size_t)b * scr_stride;
    __shared__ float lv[NCAND];
    __shared__ int   li[NCAND];
    __shared__ int   pos_s[NVIS];
    __shared__ float sc_s[NVIS];
    __shared__ float rw_s[NVIS];
    __shared__ float pacc[4][NCELL];

    for (int j = 0; j < 2; ++j) {
        int e = tid * 2 + j;
        lv[e] = scr[SCR_CV + e];
        li[e] = ((const int*)(scr + SCR_CI))[e];
    }
    __syncthreads();

    if (w == 0) {
        // final top-16 over 512 candidates (each lane owns 8)
        float v[8]; int gi[8];
        for (int j = 0; j < 8; ++j) { v[j] = lv[lane * 8 + j]; gi[j] = li[lane * 8 + j]; }
        for (int r = 0; r < NK; ++r) {
            float bv = v[0]; int bi = gi[0];
            for (int j = 1; j < 8; ++j)
                if (v[j] > bv || (v[j] == bv && gi[j] < bi)) { bv = v[j]; bi = gi[j]; }
            for (int off = 32; off >= 1; off >>= 1) {
                float ov = __shfl_xor(bv, off); int oi = __shfl_xor(bi, off);
                if (ov > bv || (ov == bv && oi < bi)) { bv = ov; bi = oi; }
            }
            for (int j = 0; j < 8; ++j)
                if (gi[j] == bi) { v[j] = -FLT_MAX; gi[j] = 0x7fffffff; }
            if (lane == 0) { pos_s[r] = bi & (NMEM - 1); sc_s[r] = bv; }
        }
        // least-used position score: dot(rq, mem[lum]) across 64 lanes
        int p16 = lum[b] & (NMEM - 1);
        float x = mem[((size_t)b * NMEM + p16) * NCELL + lane] * scr[SCR_RQ + lane];
        for (int off = 32; off >= 1; off >>= 1) x += __shfl_xor(x, off);
        if (lane == 0) { pos_s[NK] = p16; sc_s[NK] = x; }
    }
    __syncthreads();

    if (w == 0) {
        // softmax over 17 scores
        float sc = (lane < NVIS) ? sc_s[lane] : -FLT_MAX;
        float mx = sc;
        for (int off = 32; off >= 1; off >>= 1) mx = fmaxf(mx, __shfl_xor(mx, off));
        float e = (lane < NVIS) ? expf(sc - mx) : 0.f;
        float sum = e;
        for (int off = 32; off >= 1; off >>= 1) sum += __shfl_xor(sum, off);
        if (lane < NVIS) rw_s[lane] = e / sum;
    }
    __syncthreads();

    if (kc_zero) {
        // fallback: zero own RW row here (scratch lived in it; now staged)
        for (int it = 0; it < 128; ++it)
            rwrow[it * 256 + tid] = 0.f;
    }

    // visible copy + read_vectors partials (wave w takes rows w, w+4, ...)
    float acc = 0.f;
    for (int vv = w; vv < NVIS; vv += 4) {
        int p = pos_s[vv] & (NMEM - 1);
        float hv = mem[((size_t)b * NMEM + p) * NCELL + lane];
        out[OFF_VIS + ((size_t)b * NVIS + vv) * NCELL + lane] = hv;  // exact passthrough
        acc = fmaf(rw_s[vv], hv, acc);
    }
    pacc[w][lane] = acc;
    __syncthreads();

    if (tid < NCELL) {
        float s = pacc[0][tid] + pacc[1][tid] + pacc[2][tid] + pacc[3][tid];
        out[OFF_RV + b * NCELL + tid] = s;
    }
    // scatter read weights (lum = last position wins duplicates, np semantics)
    if (tid < NVIS) {
        int p = pos_s[tid] & (NMEM - 1);
        bool dup = (tid < NK) && (p == pos_s[NK]);
        if (!dup) rwrow[p] = rw_s[tid];
    }
}

extern "C" void kernel_launch(void* const* d_in, const int* in_sizes, int n_in,
                              void* d_out, int out_size, void* d_ws, size_t ws_size,
                              hipStream_t stream)
{
    const float* xi  = (const float*)d_in[0];
    const float* mem = (const float*)d_in[1];
    const int*   lum = (const int*)d_in[2];
    const float* Wrq = (const float*)d_in[3];
    const float* brq = (const float*)d_in[4];
    const float* Wwv = (const float*)d_in[5];
    const float* bwv = (const float*)d_in[6];
    const float* Wig = (const float*)d_in[7];
    const float* big = (const float*)d_in[8];
    const float* Wwg = (const float*)d_in[9];
    const float* bwg = (const float*)d_in[10];
    float* out = (float*)d_out;

    // Scratch: d_ws if big enough, else inside the RW output region (round-8
    // validated fallback).
    bool use_ws = (d_ws != nullptr) && (ws_size >= (size_t)NB * SCR_STRIDE_WS * 4);
    float* scrb = use_ws ? (float*)d_ws : out + OFF_RW;
    int    scrs = use_ws ? SCR_STRIDE_WS : NMEM;
    int    kb_zero = use_ws ? 1 : 0;   // ws mode: kB zeroes RW slices in parallel
    int    kc_zero = use_ws ? 0 : 1;   // fallback: kC zeroes (round-8 behavior)

    kA<<<dim3(NB, 5), dim3(256), 0, stream>>>(xi, Wrq, brq, Wwv, bwv, Wig, big,
                                              Wwg, bwg, scrb, scrs, out);
    kB<<<dim3(NBLK, NB), dim3(256), 0, stream>>>(mem, scrb, scrs, kb_zero, out);
    kC<<<dim3(NB), dim3(256), 0, stream>>>(mem, lum, scrb, scrs, kc_zero, out);
}

// Round 14
// 90.549 us; speedup vs baseline: 1.4328x; 1.0463x over previous
//
#include <hip/hip_runtime.h>
#include <cstdint>
#include <cstddef>
#include <cfloat>
#include <cmath>

#define NB    32
#define NIN   512
#define NMEM  32768
#define NCELL 64
#define NVIS  17
#define NK    16
#define NBLK  32               // stage-1 blocks per batch
#define RPB   (NMEM / NBLK)    // 1024 rows per block
#define NCAND (NBLK * NK)      // 512 candidates per batch

// output flat layout (f32 elements)
#define OFF_RV  0
#define OFF_RW  2048
#define OFF_VIS 1050624
#define OFF_WV  1085440
#define OFF_IG  1087488
#define OFF_WG  1088032

// scratch layout (f32-element offsets from scr_base + b*scr_stride)
#define SCR_RQ  0       // 64 f32
#define SCR_CV  64      // 512 f32
#define SCR_CI  576     // 512 i32  (ends 1088)
#define SCR_STRIDE_WS 1088

// ---------------- A: interface GEMVs, grid (NB, 5 row-groups) ---------------
__global__ __launch_bounds__(256) void kA(
    const float* __restrict__ xi,
    const float* __restrict__ Wrq, const float* __restrict__ brq,
    const float* __restrict__ Wwv, const float* __restrict__ bwv,
    const float* __restrict__ Wig, const float* __restrict__ big,
    const float* __restrict__ Wwg, const float* __restrict__ bwg,
    float* __restrict__ scr_base, int scr_stride,
    float* __restrict__ out)
{
    int b = blockIdx.x;
    int tid = threadIdx.x;
    float* rq_scr = scr_base + (size_t)b * scr_stride + SCR_RQ;
    __shared__ float sxi[NIN];
    for (int i = tid; i < NIN; i += 256)
        sxi[i] = xi[(size_t)b * NIN + i];
    __syncthreads();
    int g = tid >> 3, sub = tid & 7;          // 8 lanes per row, 32 rows/block
    int row = blockIdx.y * 32 + g;
    if (row < 146) {
        const float* W; float bias; int kind, r;
        if (row < 64)       { r = row;       W = Wrq + (size_t)r * NIN; bias = brq[r]; kind = 0; }
        else if (row < 128) { r = row - 64;  W = Wwv + (size_t)r * NIN; bias = bwv[r]; kind = 1; }
        else if (row < 145) { r = row - 128; W = Wig + (size_t)r * NIN; bias = big[r]; kind = 2; }
        else                { r = 0;         W = Wwg;                   bias = bwg[0]; kind = 3; }
        float acc = 0.f;
        const float* wp = W   + sub * 64;
        const float* xp = sxi + sub * 64;
        for (int j = 0; j < 64; ++j)
            acc = fmaf(wp[j], xp[j], acc);
        acc += __shfl_xor(acc, 1);
        acc += __shfl_xor(acc, 2);
        acc += __shfl_xor(acc, 4);
        if (sub == 0) {
            float x = acc + bias;
            if (kind == 0)      rq_scr[r] = tanhf(x);
            else if (kind == 1) out[OFF_WV + b * NCELL + r] = tanhf(x);
            else if (kind == 2) out[OFF_IG + b * NVIS + r]  = 1.f / (1.f + expf(-x));
            else                out[OFF_WG + b]             = 1.f / (1.f + expf(-x));
        }
    }
}

// ---------------- B: fused sims + hierarchical per-block top-16 -------------
// grid (NBLK, NB). 8 lanes/row; SOFTWARE-PIPELINED stream: each iteration
// issues the NEXT 16 rows' loads before computing the current 16 rows, so
// HBM latency hides under compute instead of convoy-stalling.
__global__ __launch_bounds__(256) void kB(
    const float* __restrict__ mem,
    float* __restrict__ scr_base, int scr_stride, int kb_zero,
    float* __restrict__ out)
{
    int b   = blockIdx.y;
    int blk = blockIdx.x;
    int tid = threadIdx.x;
    int w = tid >> 6, lane = tid & 63;
    int sub = lane & 7, grp = lane >> 3;
    float* scr = scr_base + (size_t)b * scr_stride;
    __shared__ float ssim[4][256];
    __shared__ float wcv[64];
    __shared__ int   wci[64];

    if (kb_zero) {
        // zero own 1024-float slice of batch b's read_weights row
        float4 z; z.x = z.y = z.z = z.w = 0.f;
        ((float4*)(out + OFF_RW + (size_t)b * NMEM + blk * RPB))[tid] = z;
    }

    float rqv[8];
    for (int e = 0; e < 8; ++e) rqv[e] = scr[SCR_RQ + sub * 8 + e];

    const float* mb = mem + (size_t)b * NMEM * NCELL + (size_t)(blk * RPB + w * 256) * NCELL;
    // lane's base within a 16-row tile: set A = row grp, set B = row 8+grp
    const float* p = mb + grp * NCELL + sub * 8;

    auto compute = [&](int it, float4 a0, float4 d0, float4 a1, float4 d1) {
        float s0 = 0.f, s1 = 0.f;
        s0 = fmaf(a0.x, rqv[0], s0); s0 = fmaf(a0.y, rqv[1], s0);
        s0 = fmaf(a0.z, rqv[2], s0); s0 = fmaf(a0.w, rqv[3], s0);
        s0 = fmaf(d0.x, rqv[4], s0); s0 = fmaf(d0.y, rqv[5], s0);
        s0 = fmaf(d0.z, rqv[6], s0); s0 = fmaf(d0.w, rqv[7], s0);
        s1 = fmaf(a1.x, rqv[0], s1); s1 = fmaf(a1.y, rqv[1], s1);
        s1 = fmaf(a1.z, rqv[2], s1); s1 = fmaf(a1.w, rqv[3], s1);
        s1 = fmaf(d1.x, rqv[4], s1); s1 = fmaf(d1.y, rqv[5], s1);
        s1 = fmaf(d1.z, rqv[6], s1); s1 = fmaf(d1.w, rqv[7], s1);
        s0 += __shfl_xor(s0, 1); s0 += __shfl_xor(s0, 2); s0 += __shfl_xor(s0, 4);
        s1 += __shfl_xor(s1, 1); s1 += __shfl_xor(s1, 2); s1 += __shfl_xor(s1, 4);
        if (sub == 0) {
            ssim[w][it * 16 + grp]     = s0;
            ssim[w][it * 16 + 8 + grp] = s1;
        }
    };

    // prologue: loads for tile 0 (rows 0..15)
    float4 ca0 = *(const float4*)(p);
    float4 cd0 = *(const float4*)(p + 4);
    float4 ca1 = *(const float4*)(p + 8 * NCELL);
    float4 cd1 = *(const float4*)(p + 8 * NCELL + 4);

    for (int it = 0; it < 15; ++it) {
        const float* np = p + (size_t)(it + 1) * 16 * NCELL;
        float4 na0 = *(const float4*)(np);
        float4 nd0 = *(const float4*)(np + 4);
        float4 na1 = *(const float4*)(np + 8 * NCELL);
        float4 nd1 = *(const float4*)(np + 8 * NCELL + 4);
        compute(it, ca0, cd0, ca1, cd1);
        ca0 = na0; cd0 = nd0; ca1 = na1; cd1 = nd1;
    }
    compute(15, ca0, cd0, ca1, cd1);
    __syncthreads();

    // per-wave top-16 over 256 values (each lane owns 4)
    int gbase = blk * RPB + w * 256;
    float v[4]; int gi[4];
    for (int j = 0; j < 4; ++j) {
        v[j]  = ssim[w][lane * 4 + j];
        gi[j] = gbase + lane * 4 + j;
    }
    for (int r = 0; r < NK; ++r) {
        float bv = v[0]; int bi = gi[0];
        for (int j = 1; j < 4; ++j)
            if (v[j] > bv || (v[j] == bv && gi[j] < bi)) { bv = v[j]; bi = gi[j]; }
        for (int off = 32; off >= 1; off >>= 1) {
            float ov = __shfl_xor(bv, off); int oi = __shfl_xor(bi, off);
            if (ov > bv || (ov == bv && oi < bi)) { bv = ov; bi = oi; }
        }
        for (int j = 0; j < 4; ++j)
            if (gi[j] == bi) { v[j] = -FLT_MAX; gi[j] = 0x7fffffff; }
        if (lane == 0) { wcv[w * 16 + r] = bv; wci[w * 16 + r] = bi; }
    }
    __syncthreads();

    // wave 0 merges 4x16 wave candidates -> block top-16 into scratch
    if (w == 0) {
        float mv2 = wcv[lane]; int mi2 = wci[lane];
        float* ovp = scr + SCR_CV + blk * NK;
        int*   oip = (int*)(scr + SCR_CI) + blk * NK;
        for (int r = 0; r < NK; ++r) {
            float bv = mv2; int bi = mi2;
            for (int off = 32; off >= 1; off >>= 1) {
                float ov = __shfl_xor(bv, off); int oi = __shfl_xor(bi, off);
                if (ov > bv || (ov == bv && oi < bi)) { bv = ov; bi = oi; }
            }
            if (mi2 == bi) { mv2 = -FLT_MAX; mi2 = 0x7fffffff; }
            if (lane == 0) { ovp[r] = bv; oip[r] = bi; }
        }
    }
}

// ------- C: final top-16, lum score, softmax, (zero+)scatter, RV/VIS --------
__global__ __launch_bounds__(256) void kC(
    const float* __restrict__ mem, const int* __restrict__ lum,
    const float* __restrict__ scr_base, int scr_stride, int kc_zero,
    float* __restrict__ out)
{
    int b = blockIdx.x;
    int tid = threadIdx.x;
    int w = tid >> 6, lane = tid & 63;
    float* rwrow = out + OFF_RW + (size_t)b * NMEM;
    const float* scr = scr_base + (size_t)b * scr_stride;
    __shared__ float lv[NCAND];
    __shared__ int   li[NCAND];
    __shared__ int   pos_s[NVIS];
    __shared__ float sc_s[NVIS];
    __shared__ float rw_s[NVIS];
    __shared__ float pacc[4][NCELL];

    for (int j = 0; j < 2; ++j) {
        int e = tid * 2 + j;
        lv[e] = scr[SCR_CV + e];
        li[e] = ((const int*)(scr + SCR_CI))[e];
    }
    __syncthreads();

    if (w == 0) {
        // final top-16 over 512 candidates (each lane owns 8)
        float v[8]; int gi[8];
        for (int j = 0; j < 8; ++j) { v[j] = lv[lane * 8 + j]; gi[j] = li[lane * 8 + j]; }
        for (int r = 0; r < NK; ++r) {
            float bv = v[0]; int bi = gi[0];
            for (int j = 1; j < 8; ++j)
                if (v[j] > bv || (v[j] == bv && gi[j] < bi)) { bv = v[j]; bi = gi[j]; }
            for (int off = 32; off >= 1; off >>= 1) {
                float ov = __shfl_xor(bv, off); int oi = __shfl_xor(bi, off);
                if (ov > bv || (ov == bv && oi < bi)) { bv = ov; bi = oi; }
            }
            for (int j = 0; j < 8; ++j)
                if (gi[j] == bi) { v[j] = -FLT_MAX; gi[j] = 0x7fffffff; }
            if (lane == 0) { pos_s[r] = bi & (NMEM - 1); sc_s[r] = bv; }
        }
        // least-used position score: dot(rq, mem[lum]) across 64 lanes
        int p16 = lum[b] & (NMEM - 1);
        float x = mem[((size_t)b * NMEM + p16) * NCELL + lane] * scr[SCR_RQ + lane];
        for (int off = 32; off >= 1; off >>= 1) x += __shfl_xor(x, off);
        if (lane == 0) { pos_s[NK] = p16; sc_s[NK] = x; }
    }
    __syncthreads();

    if (w == 0) {
        // softmax over 17 scores
        float sc = (lane < NVIS) ? sc_s[lane] : -FLT_MAX;
        float mx = sc;
        for (int off = 32; off >= 1; off >>= 1) mx = fmaxf(mx, __shfl_xor(mx, off));
        float e = (lane < NVIS) ? expf(sc - mx) : 0.f;
        float sum = e;
        for (int off = 32; off >= 1; off >>= 1) sum += __shfl_xor(sum, off);
        if (lane < NVIS) rw_s[lane] = e / sum;
    }
    __syncthreads();

    if (kc_zero) {
        // fallback: zero own RW row here (scratch lived in it; now staged)
        for (int it = 0; it < 128; ++it)
            rwrow[it * 256 + tid] = 0.f;
    }

    // visible copy + read_vectors partials (wave w takes rows w, w+4, ...)
    float acc = 0.f;
    for (int vv = w; vv < NVIS; vv += 4) {
        int p = pos_s[vv] & (NMEM - 1);
        float hv = mem[((size_t)b * NMEM + p) * NCELL + lane];
        out[OFF_VIS + ((size_t)b * NVIS + vv) * NCELL + lane] = hv;  // exact passthrough
        acc = fmaf(rw_s[vv], hv, acc);
    }
    pacc[w][lane] = acc;
    __syncthreads();

    if (tid < NCELL) {
        float s = pacc[0][tid] + pacc[1][tid] + pacc[2][tid] + pacc[3][tid];
        out[OFF_RV + b * NCELL + tid] = s;
    }
    // scatter read weights (lum = last position wins duplicates, np semantics)
    if (tid < NVIS) {
        int p = pos_s[tid] & (NMEM - 1);
        bool dup = (tid < NK) && (p == pos_s[NK]);
        if (!dup) rwrow[p] = rw_s[tid];
    }
}

extern "C" void kernel_launch(void* const* d_in, const int* in_sizes, int n_in,
                              void* d_out, int out_size, void* d_ws, size_t ws_size,
                              hipStream_t stream)
{
    const float* xi  = (const float*)d_in[0];
    const float* mem = (const float*)d_in[1];
    const int*   lum = (const int*)d_in[2];
    const float* Wrq = (const float*)d_in[3];
    const float* brq = (const float*)d_in[4];
    const float* Wwv = (const float*)d_in[5];
    const float* bwv = (const float*)d_in[6];
    const float* Wig = (const float*)d_in[7];
    const float* big = (const float*)d_in[8];
    const float* Wwg = (const float*)d_in[9];
    const float* bwg = (const float*)d_in[10];
    float* out = (float*)d_out;

    // Scratch: d_ws if big enough, else inside the RW output region (round-8
    // validated fallback).
    bool use_ws = (d_ws != nullptr) && (ws_size >= (size_t)NB * SCR_STRIDE_WS * 4);
    float* scrb = use_ws ? (float*)d_ws : out + OFF_RW;
    int    scrs = use_ws ? SCR_STRIDE_WS : NMEM;
    int    kb_zero = use_ws ? 1 : 0;   // ws mode: kB zeroes RW slices in parallel
    int    kc_zero = use_ws ? 0 : 1;   // fallback: kC zeroes (round-8 behavior)

    kA<<<dim3(NB, 5), dim3(256), 0, stream>>>(xi, Wrq, brq, Wwv, bwv, Wig, big,
                                              Wwg, bwg, scrb, scrs, out);
    kB<<<dim3(NBLK, NB), dim3(256), 0, stream>>>(mem, scrb, scrs, kb_zero, out);
    kC<<<dim3(NB), dim3(256), 0, stream>>>(mem, lum, scrb, scrs, kc_zero, out);
}